// Round 13
// baseline (106.010 us; speedup 1.0000x reference)
//
#include <hip/hip_runtime.h>

#define NRAYS 8192
#define NS    256
#define HID   64
#define RPB   4      // rays per block, one wave per ray
#define EP    264    // E row stride in floats (16B-aligned, bank-spread)

typedef _Float16 f16x2 __attribute__((ext_vector_type(2)));
typedef _Float16 f16x8 __attribute__((ext_vector_type(8)));
typedef float    f32x4 __attribute__((ext_vector_type(4)));

__global__ __launch_bounds__(256) void vr_kernel(
    const float* __restrict__ ray_start,
    const float* __restrict__ ray_dir,
    const float* __restrict__ sampled_depth,
    const float* __restrict__ sampled_dists,
    const int*   __restrict__ sampled_idx,
    const float* __restrict__ W1,
    const float* __restrict__ b1,
    const float* __restrict__ w_sigma,
    const float* __restrict__ W_rgb,
    const float* __restrict__ W_dir,
    const float* __restrict__ b_rgb,
    float* __restrict__ out)
{
    __shared__ _Float16 sA[RPB][HID];     // per-ray A_k (f16)
    __shared__ _Float16 sB[RPB][HID];     // per-ray B_k (f16)
    __shared__ _Float16 sDep[RPB][NS];    // per-ray depths (f16)
    __shared__ float    sE[RPB][4][EP];   // per-ray mfma output, 4 channels

    const int t    = threadIdx.x;
    const int lane = t & 63;
    const int wv   = t >> 6;              // wave = ray slot
    const int ray  = blockIdx.x * RPB + wv;

    // ---- per-ray constants: A_k, B_k for hidden unit k = lane ----
    const float ox = ray_start[ray*3+0], oy = ray_start[ray*3+1], oz = ray_start[ray*3+2];
    const float dx = ray_dir[ray*3+0],  dy = ray_dir[ray*3+1],  dz = ray_dir[ray*3+2];
    {
        const int h = lane;
        const float w0 = W1[h], w1 = W1[HID + h], w2 = W1[2*HID + h];
        const float A = fmaf(w0, ox, fmaf(w1, oy, fmaf(w2, oz, b1[h])));
        const float B = fmaf(w0, dx, fmaf(w1, dy, w2 * dz));
        sA[wv][h] = (_Float16)A;
        sB[wv][h] = (_Float16)B;
    }

    // view-dependent rgb bias (wave-uniform)
    const float dwr = fmaf(dx, W_dir[0], fmaf(dy, W_dir[3], fmaf(dz, W_dir[6], b_rgb[0])));
    const float dwg = fmaf(dx, W_dir[1], fmaf(dy, W_dir[4], fmaf(dz, W_dir[7], b_rgb[1])));
    const float dwb = fmaf(dx, W_dir[2], fmaf(dy, W_dir[5], fmaf(dz, W_dir[8], b_rgb[2])));

    // ---- own samples 4*lane .. 4*lane+3 ----
    const size_t rbase = (size_t)ray * NS + (size_t)lane * 4;
    const float4 dep = *(const float4*)(sampled_depth + rbase);
    const float4 dst = *(const float4*)(sampled_dists + rbase);
    const int4  vidx = *(const int4*)(sampled_idx + rbase);

    {   // stage depths as f16
        f16x2 dl; dl.x = (_Float16)dep.x; dl.y = (_Float16)dep.y;
        f16x2 dh; dh.x = (_Float16)dep.z; dh.y = (_Float16)dep.w;
        f16x2* dp = (f16x2*)&sDep[wv][4*lane];
        dp[0] = dl; dp[1] = dh;
    }

    // ---- B-fragment (Wout, grid-uniform): B[k][n], n=lane&15, k=(lane>>4)*8+j ----
    const int n = lane & 15;
    const int q = lane >> 4;
    f16x8 bflo = (f16x8)(_Float16)0.f;
    f16x8 bfhi = (f16x8)(_Float16)0.f;
    if (n < 4) {
#pragma unroll
        for (int j = 0; j < 8; ++j) {
            const int klo = q*8 + j, khi = 32 + q*8 + j;
            const float vlo = (n == 0) ? w_sigma[klo] : W_rgb[klo*3 + (n-1)];
            const float vhi = (n == 0) ? w_sigma[khi] : W_rgb[khi*3 + (n-1)];
            bflo[j] = (_Float16)vlo;
            bfhi[j] = (_Float16)vhi;
        }
    }
    __syncthreads();

    // ---- lane's ray constants for its 16 k's (A-frag k-slots) ----
    const f16x8 Alo = *(const f16x8*)&sA[wv][q*8];
    const f16x8 Ahi = *(const f16x8*)&sA[wv][32 + q*8];
    const f16x8 Blo = *(const f16x8*)&sB[wv][q*8];
    const f16x8 Bhi = *(const f16x8*)&sB[wv][32 + q*8];
    const f16x8 z8  = (f16x8)(_Float16)0.f;

    // ---- main loop: 16 M-tiles of 16 samples, K=64 via 2 mfma ----
#pragma unroll
    for (int tt = 0; tt < 16; ++tt) {
        const _Float16 dv = sDep[wv][16*tt + n];   // depth of sample m = n
        f16x8 d8;
#pragma unroll
        for (int j = 0; j < 8; ++j) d8[j] = dv;
        f16x8 hlo = __builtin_elementwise_fma(Blo, d8, Alo);   // v_pk_fma_f16
        f16x8 hhi = __builtin_elementwise_fma(Bhi, d8, Ahi);
        hlo = __builtin_elementwise_max(hlo, z8);              // relu
        hhi = __builtin_elementwise_max(hhi, z8);
        f32x4 acc = {0.f, 0.f, 0.f, 0.f};
        acc = __builtin_amdgcn_mfma_f32_16x16x32_f16(hlo, bflo, acc, 0, 0, 0);
        acc = __builtin_amdgcn_mfma_f32_16x16x32_f16(hhi, bfhi, acc, 0, 0, 0);
        // C layout: col=lane&15 (channel), rows (lane>>4)*4+reg (samples)
        if (n < 4)
            *(f32x4*)&sE[wv][n][16*tt + 4*q] = acc;
    }
    __syncthreads();   // intra-wave LDS ordering safety (cheap)

    // ---- epilogue: thread owns samples 4*lane .. 4*lane+3 ----
    const f32x4 sg4 = *(const f32x4*)&sE[wv][0][4*lane];
    const f32x4 cr4 = *(const f32x4*)&sE[wv][1][4*lane];
    const f32x4 cg4 = *(const f32x4*)&sE[wv][2][4*lane];
    const f32x4 cb4 = *(const f32x4*)&sE[wv][3][4*lane];

    const float dpt[4] = {dep.x, dep.y, dep.z, dep.w};
    const float dsv[4] = {dst.x, dst.y, dst.z, dst.w};
    const int   vid[4] = {vidx.x, vidx.y, vidx.z, vidx.w};

    float c[4];
    float run = 0.f;
#pragma unroll
    for (int j = 0; j < 4; ++j) {
        float f = fmaxf(sg4[j], 0.f) * dsv[j] * 7.0f;
        if (vid[j] == -1) f = 0.f;
        run += f;
        c[j] = run;
    }

    // wave-level (width 64) exclusive scan of per-thread totals
    float tot = run;
#pragma unroll
    for (int off = 1; off < 64; off <<= 1) {
        const float v = __shfl_up(tot, off, 64);
        if (lane >= off) tot += v;
    }
    const float base = tot - run;

    // telescoped probs
    float Eprev = __expf(-base);
    float prob[4];
    float s0 = 0.f, s1 = 0.f, s2 = 0.f, s3 = 0.f, s4 = 0.f;
#pragma unroll
    for (int j = 0; j < 4; ++j) {
        const float Ej = __expf(-(base + c[j]));
        const float p  = Eprev - Ej;
        Eprev = Ej;
        prob[j] = p;
        const float rr = __builtin_amdgcn_rcpf(1.f + __expf(-(cr4[j] + dwr)));
        const float gg = __builtin_amdgcn_rcpf(1.f + __expf(-(cg4[j] + dwg)));
        const float bb = __builtin_amdgcn_rcpf(1.f + __expf(-(cb4[j] + dwb)));
        s0 += p;
        s1 = fmaf(dpt[j], p, s1);
        s2 = fmaf(rr, p, s2);
        s3 = fmaf(gg, p, s3);
        s4 = fmaf(bb, p, s4);
    }

    // store probs before the reduction (overlap store latency)
    float* orow = out + (size_t)ray * (NS + 5);
#pragma unroll
    for (int j = 0; j < 4; ++j)
        orow[5 + 4*lane + j] = prob[j];

    // wave reduction of the 5 sums
#pragma unroll
    for (int off = 32; off >= 1; off >>= 1) {
        s0 += __shfl_xor(s0, off, 64);
        s1 += __shfl_xor(s1, off, 64);
        s2 += __shfl_xor(s2, off, 64);
        s3 += __shfl_xor(s3, off, 64);
        s4 += __shfl_xor(s4, off, 64);
    }

    if (lane == 0) {
        orow[0] = s2;          // r
        orow[1] = s3;          // g
        orow[2] = s4;          // b
        orow[3] = s1;          // depth
        orow[4] = 1.f - s0;    // missed
    }
}

extern "C" void kernel_launch(void* const* d_in, const int* in_sizes, int n_in,
                              void* d_out, int out_size, void* d_ws, size_t ws_size,
                              hipStream_t stream)
{
    vr_kernel<<<NRAYS / RPB, 256, 0, stream>>>(
        (const float*)d_in[0],   // ray_start
        (const float*)d_in[1],   // ray_dir
        (const float*)d_in[2],   // sampled_depth
        (const float*)d_in[3],   // sampled_dists
        (const int*)  d_in[4],   // sampled_idx
        (const float*)d_in[5],   // W1
        (const float*)d_in[6],   // b1
        (const float*)d_in[7],   // w_sigma
        (const float*)d_in[8],   // W_rgb
        (const float*)d_in[9],   // W_dir
        (const float*)d_in[10],  // b_rgb
        (float*)d_out);
}

// Round 14
// 104.829 us; speedup vs baseline: 1.0113x; 1.0113x over previous
//
#include <hip/hip_runtime.h>

#define NRAYS 8192
#define NS    256
#define HID   64
#define RPB   4      // rays per block, one wave per ray
#define EP    260    // E row stride in floats (16B-aligned stride: 1040 B)

typedef _Float16 f16x2 __attribute__((ext_vector_type(2)));
typedef _Float16 f16x8 __attribute__((ext_vector_type(8)));
typedef float    f32x4 __attribute__((ext_vector_type(4)));

// same-wave LDS ordering: DS ops complete in order; wait lgkm then resume.
// (NOT a block barrier -- avoids the s_waitcnt vmcnt(0) drain a s_barrier forces.)
#define WAVE_LDS_FENCE() asm volatile("s_waitcnt lgkmcnt(0)" ::: "memory")

__global__ __launch_bounds__(256) void vr_kernel(
    const float* __restrict__ ray_start,
    const float* __restrict__ ray_dir,
    const float* __restrict__ sampled_depth,
    const float* __restrict__ sampled_dists,
    const int*   __restrict__ sampled_idx,
    const float* __restrict__ W1,
    const float* __restrict__ b1,
    const float* __restrict__ w_sigma,
    const float* __restrict__ W_rgb,
    const float* __restrict__ W_dir,
    const float* __restrict__ b_rgb,
    float* __restrict__ out)
{
    // ALL LDS regions are produced and consumed by the SAME wave (indexed by wv):
    // no __syncthreads anywhere in this kernel.
    __shared__ _Float16 sA[RPB][HID];     // per-ray A_k (f16)
    __shared__ _Float16 sB[RPB][HID];     // per-ray B_k (f16)
    __shared__ _Float16 sDep[RPB][NS];    // per-ray depths (f16)
    __shared__ float    sE[RPB][4][EP];   // per-ray mfma output, 4 channels

    const int t    = threadIdx.x;
    const int lane = t & 63;
    const int wv   = t >> 6;              // wave = ray slot
    const int ray  = blockIdx.x * RPB + wv;

    // ---- per-ray constants: A_k, B_k for hidden unit k = lane ----
    const float ox = ray_start[ray*3+0], oy = ray_start[ray*3+1], oz = ray_start[ray*3+2];
    const float dx = ray_dir[ray*3+0],  dy = ray_dir[ray*3+1],  dz = ray_dir[ray*3+2];
    {
        const int h = lane;
        const float w0 = W1[h], w1 = W1[HID + h], w2 = W1[2*HID + h];
        const float A = fmaf(w0, ox, fmaf(w1, oy, fmaf(w2, oz, b1[h])));
        const float B = fmaf(w0, dx, fmaf(w1, dy, w2 * dz));
        sA[wv][h] = (_Float16)A;
        sB[wv][h] = (_Float16)B;
    }

    // view-dependent rgb bias (wave-uniform)
    const float dwr = fmaf(dx, W_dir[0], fmaf(dy, W_dir[3], fmaf(dz, W_dir[6], b_rgb[0])));
    const float dwg = fmaf(dx, W_dir[1], fmaf(dy, W_dir[4], fmaf(dz, W_dir[7], b_rgb[1])));
    const float dwb = fmaf(dx, W_dir[2], fmaf(dy, W_dir[5], fmaf(dz, W_dir[8], b_rgb[2])));

    // ---- own samples 4*lane .. 4*lane+3 (loads may stay in flight until epilogue) ----
    const size_t rbase = (size_t)ray * NS + (size_t)lane * 4;
    const float4 dep = *(const float4*)(sampled_depth + rbase);
    const float4 dst = *(const float4*)(sampled_dists + rbase);
    const int4  vidx = *(const int4*)(sampled_idx + rbase);

    {   // stage depths as f16 (same-wave consumer)
        f16x2 dl; dl.x = (_Float16)dep.x; dl.y = (_Float16)dep.y;
        f16x2 dh; dh.x = (_Float16)dep.z; dh.y = (_Float16)dep.w;
        f16x2* dp = (f16x2*)&sDep[wv][4*lane];
        dp[0] = dl; dp[1] = dh;
    }

    // ---- B-fragment (Wout, grid-uniform) built straight from global:
    //      B[k][n], n=lane&15, k=(lane>>4)*8+j ----
    const int n = lane & 15;
    const int q = lane >> 4;
    f16x8 bflo = (f16x8)(_Float16)0.f;
    f16x8 bfhi = (f16x8)(_Float16)0.f;
    if (n < 4) {
#pragma unroll
        for (int j = 0; j < 8; ++j) {
            const int klo = q*8 + j, khi = 32 + q*8 + j;
            const float vlo = (n == 0) ? w_sigma[klo] : W_rgb[klo*3 + (n-1)];
            const float vhi = (n == 0) ? w_sigma[khi] : W_rgb[khi*3 + (n-1)];
            bflo[j] = (_Float16)vlo;
            bfhi[j] = (_Float16)vhi;
        }
    }

    WAVE_LDS_FENCE();   // sA/sB/sDep visible to this wave's lanes

    // ---- lane's ray constants for its 16 k's (A-frag k-slots) ----
    const f16x8 Alo = *(const f16x8*)&sA[wv][q*8];
    const f16x8 Ahi = *(const f16x8*)&sA[wv][32 + q*8];
    const f16x8 Blo = *(const f16x8*)&sB[wv][q*8];
    const f16x8 Bhi = *(const f16x8*)&sB[wv][32 + q*8];
    const f16x8 z8  = (f16x8)(_Float16)0.f;

    // ---- main loop: 16 M-tiles of 16 samples, K=64 via 2 mfma ----
#pragma unroll
    for (int tt = 0; tt < 16; ++tt) {
        const _Float16 dv = sDep[wv][16*tt + n];   // depth of sample m = n
        f16x8 d8;
#pragma unroll
        for (int j = 0; j < 8; ++j) d8[j] = dv;
        f16x8 hlo = __builtin_elementwise_fma(Blo, d8, Alo);   // v_pk_fma_f16
        f16x8 hhi = __builtin_elementwise_fma(Bhi, d8, Ahi);
        hlo = __builtin_elementwise_max(hlo, z8);              // relu
        hhi = __builtin_elementwise_max(hhi, z8);
        f32x4 acc = {0.f, 0.f, 0.f, 0.f};
        acc = __builtin_amdgcn_mfma_f32_16x16x32_f16(hlo, bflo, acc, 0, 0, 0);
        acc = __builtin_amdgcn_mfma_f32_16x16x32_f16(hhi, bfhi, acc, 0, 0, 0);
        // C layout: col=lane&15 (channel), rows (lane>>4)*4+reg (samples)
        if (n < 4)
            *(f32x4*)&sE[wv][n][16*tt + 4*q] = acc;
    }

    WAVE_LDS_FENCE();   // sE transpose visible within the wave

    // ---- epilogue: thread owns samples 4*lane .. 4*lane+3 ----
    const f32x4 sg4 = *(const f32x4*)&sE[wv][0][4*lane];
    const f32x4 cr4 = *(const f32x4*)&sE[wv][1][4*lane];
    const f32x4 cg4 = *(const f32x4*)&sE[wv][2][4*lane];
    const f32x4 cb4 = *(const f32x4*)&sE[wv][3][4*lane];

    const float dpt[4] = {dep.x, dep.y, dep.z, dep.w};
    const float dsv[4] = {dst.x, dst.y, dst.z, dst.w};
    const int   vid[4] = {vidx.x, vidx.y, vidx.z, vidx.w};

    float c[4];
    float run = 0.f;
#pragma unroll
    for (int j = 0; j < 4; ++j) {
        float f = fmaxf(sg4[j], 0.f) * dsv[j] * 7.0f;
        if (vid[j] == -1) f = 0.f;
        run += f;
        c[j] = run;
    }

    // wave-level (width 64) exclusive scan of per-thread totals
    float tot = run;
#pragma unroll
    for (int off = 1; off < 64; off <<= 1) {
        const float v = __shfl_up(tot, off, 64);
        if (lane >= off) tot += v;
    }
    const float base = tot - run;

    // telescoped probs
    float Eprev = __expf(-base);
    float prob[4];
    float s0 = 0.f, s1 = 0.f, s2 = 0.f, s3 = 0.f, s4 = 0.f;
#pragma unroll
    for (int j = 0; j < 4; ++j) {
        const float Ej = __expf(-(base + c[j]));
        const float p  = Eprev - Ej;
        Eprev = Ej;
        prob[j] = p;
        const float rr = __builtin_amdgcn_rcpf(1.f + __expf(-(cr4[j] + dwr)));
        const float gg = __builtin_amdgcn_rcpf(1.f + __expf(-(cg4[j] + dwg)));
        const float bb = __builtin_amdgcn_rcpf(1.f + __expf(-(cb4[j] + dwb)));
        s0 += p;
        s1 = fmaf(dpt[j], p, s1);
        s2 = fmaf(rr, p, s2);
        s3 = fmaf(gg, p, s3);
        s4 = fmaf(bb, p, s4);
    }

    // store probs before the reduction (overlap store latency with shuffles)
    float* orow = out + (size_t)ray * (NS + 5);
#pragma unroll
    for (int j = 0; j < 4; ++j)
        orow[5 + 4*lane + j] = prob[j];

    // wave reduction of the 5 sums
#pragma unroll
    for (int off = 32; off >= 1; off >>= 1) {
        s0 += __shfl_xor(s0, off, 64);
        s1 += __shfl_xor(s1, off, 64);
        s2 += __shfl_xor(s2, off, 64);
        s3 += __shfl_xor(s3, off, 64);
        s4 += __shfl_xor(s4, off, 64);
    }

    if (lane == 0) {
        orow[0] = s2;          // r
        orow[1] = s3;          // g
        orow[2] = s4;          // b
        orow[3] = s1;          // depth
        orow[4] = 1.f - s0;    // missed
    }
}

extern "C" void kernel_launch(void* const* d_in, const int* in_sizes, int n_in,
                              void* d_out, int out_size, void* d_ws, size_t ws_size,
                              hipStream_t stream)
{
    vr_kernel<<<NRAYS / RPB, 256, 0, stream>>>(
        (const float*)d_in[0],   // ray_start
        (const float*)d_in[1],   // ray_dir
        (const float*)d_in[2],   // sampled_depth
        (const float*)d_in[3],   // sampled_dists
        (const int*)  d_in[4],   // sampled_idx
        (const float*)d_in[5],   // W1
        (const float*)d_in[6],   // b1
        (const float*)d_in[7],   // w_sigma
        (const float*)d_in[8],   // W_rgb
        (const float*)d_in[9],   // W_dir
        (const float*)d_in[10],  // b_rgb
        (float*)d_out);
}